// Round 1
// 880.050 us; speedup vs baseline: 1.0558x; 1.0558x over previous
//
#include <hip/hip_runtime.h>
#include <hip/hip_bf16.h>
#include <cstdint>
#include <cstddef>

// Problem constants
constexpr int   Bm = 1024;      // batch (M)
constexpr int   Dk = 512;       // feature dim (K)
constexpr int   Cn = 100000;    // classes (N)
constexpr float S_SCALE = 30.0f;
constexpr float MARGIN  = 0.4f;

static_assert(Cn % 4 == 0, "N must be multiple of 4 for float4 loads");

typedef __bf16 bf16_t;
typedef __bf16 bf16x4 __attribute__((ext_vector_type(4)));
typedef __bf16 bf16x8 __attribute__((ext_vector_type(8)));
typedef float  f32x4  __attribute__((ext_vector_type(4)));

constexpr int BN    = 128;                  // N tile
constexpr int NT    = (Cn + BN - 1) / BN;   // 782 n-tiles
constexpr int NTP   = 784;                  // padded partials stride

// fast-path workspace layout
constexpr size_t WBFT_B    = (size_t)Cn * Dk * 2;   // 102,400,000 B (normalized W^T bf16)
constexpr size_t XBF_B     = (size_t)Bm * Dk * 2;   // 1 MiB
constexpr size_t PART_B    = (size_t)Bm * NTP * 4;  // 3,211,264 B
constexpr size_t NEED_FAST = WBFT_B + XBF_B + PART_B + 4096;

// legacy-path constants
constexpr int BK_L    = 32;
constexpr int NSTEP_L = Dk / BK_L;          // 16
constexpr int LDB_L   = 40;

// ---------------------------------------------------------------------------
// prep: L2-normalize rows of x, store bf16. One wave per row.
// ---------------------------------------------------------------------------
__global__ __launch_bounds__(64) void k_prep_x(const float* __restrict__ x,
                                               bf16_t* __restrict__ Xbf) {
    const int row  = blockIdx.x;
    const int lane = threadIdx.x;
    const float* xp = x + (size_t)row * Dk + lane * 8;
    float4 a = *(const float4*)xp;
    float4 b = *(const float4*)(xp + 4);
    float s = a.x*a.x + a.y*a.y + a.z*a.z + a.w*a.w
            + b.x*b.x + b.y*b.y + b.z*b.z + b.w*b.w;
    #pragma unroll
    for (int off = 1; off < 64; off <<= 1) s += __shfl_xor(s, off);
    const float inv = rsqrtf(fmaxf(s, 1e-24f));   // == 1/clip(||x||,1e-12)
    bf16x8 v;
    v[0] = (bf16_t)(a.x * inv); v[1] = (bf16_t)(a.y * inv);
    v[2] = (bf16_t)(a.z * inv); v[3] = (bf16_t)(a.w * inv);
    v[4] = (bf16_t)(b.x * inv); v[5] = (bf16_t)(b.y * inv);
    v[6] = (bf16_t)(b.z * inv); v[7] = (bf16_t)(b.w * inv);
    *(bf16x8*)(Xbf + (size_t)row * Dk + lane * 8) = v;
}

// ---------------------------------------------------------------------------
// prep W (fast path): per-column L2 norm (fp32, matches reference), then write
// WbfT[c][k] = bf16(W[k][c] / ||w_c||)  -- transposed, k-contiguous rows (1KB).
// Block = 256 threads handles 64 columns. Column chunk is read twice: once for
// the norm (HBM) and once for the normalized write (L2/L3-hot re-read), so the
// bf16 rounding happens exactly once (scale-then-round).
// ---------------------------------------------------------------------------
constexpr int PC = 64;   // columns per block
__global__ __launch_bounds__(256) void k_prep_w(const float* __restrict__ W,
                                                bf16_t* __restrict__ WbfT) {
    __shared__ alignas(16) bf16_t T[PC * Dk];   // 64 KiB, slot-swizzled rows
    __shared__ float nsqb[PC][4];
    __shared__ float invn[PC];

    const int c0  = blockIdx.x * PC;
    const int t   = threadIdx.x;
    const int col = t & 63, kg = t >> 6;        // 4 k-groups of 128
    const int c   = c0 + col;
    const bool cv = c < Cn;
    const float* p = W + (size_t)(kg * 128) * Cn + c;

    float nsq = 0.f;
    if (cv) {
        #pragma unroll 8
        for (int i = 0; i < 128; ++i) {
            const float v = p[(size_t)i * Cn];
            nsq += v * v;
        }
    }
    nsqb[col][kg] = nsq;
    __syncthreads();
    if (t < PC)
        invn[t] = rsqrtf(fmaxf(nsqb[t][0] + nsqb[t][1] + nsqb[t][2] + nsqb[t][3], 1e-24f));
    __syncthreads();

    const float inv = invn[col];
    if (cv) {
        #pragma unroll 2
        for (int s = 0; s < 16; ++s) {          // 16 slots of 8 k each per k-group
            bf16x8 v;
            #pragma unroll
            for (int j = 0; j < 8; ++j)
                v[j] = (bf16_t)(p[(size_t)(s * 8 + j) * Cn] * inv);
            const int slot = (kg * 16 + s) ^ (col & 7);   // XOR-swizzle (bank spread)
            *(bf16x8*)&T[col * Dk + slot * 8] = v;
        }
    }
    __syncthreads();

    // write out: each wave writes full 1KB rows, lane l = 16B chunk l (coalesced)
    const int wv = t >> 6, l = t & 63;
    #pragma unroll 4
    for (int rr = 0; rr < 16; ++rr) {
        const int r  = wv * 16 + rr;
        const int cc = c0 + r;
        if (cc < Cn) {
            bf16x8 v = *(const bf16x8*)&T[r * Dk + ((l ^ (r & 7)) * 8)];
            *(bf16x8*)(WbfT + (size_t)cc * Dk + l * 8) = v;
        }
    }
}

// ---------------------------------------------------------------------------
// fast GEMM: cossim = clip(Xn @ WnT^T, +-1); per-row partial exp-sums to part.
// B staged via global_load_lds (width 16) into XOR-swizzled LDS; A fragments
// direct from global (Xbf is 1MB, L2-resident, reused 782x). Two barriers per
// K-step; next-tile staging issued after the read-barrier so it overlaps MFMA.
// Grid mapping: id%8 -> XCD; 8 m-blocks of one n-tile land on ONE XCD.
// ---------------------------------------------------------------------------
__global__ __launch_bounds__(256) void k_gemm(const bf16_t* __restrict__ WbfT,
                                              const bf16_t* __restrict__ Xbf,
                                              float* __restrict__ out,
                                              float* __restrict__ part) {
    __shared__ alignas(16) bf16_t Blds[BN * 64];   // 16KB: [n][k] rows of 128B, swizzled
    __shared__ float rsbuf[128 * 2];

    const int id  = blockIdx.x;
    const int nt  = (id >> 6) * 8 + (id & 7);
    const int mt8 = (id >> 3) & 7;
    if (nt >= NT) return;
    const int n0 = nt * BN;
    const int m0 = mt8 * 128;

    const int tid  = threadIdx.x;
    const int wave = tid >> 6, lane = tid & 63;
    const int wm   = wave >> 1, wn = wave & 1;
    const int quad = lane >> 4, l16 = lane & 15;

    // staging: iteration it covers LDS bytes [it*4096 + wave*1024 + lane*16].
    // dest row n = it*32 + wave*8 + (lane>>3), dest slot = lane&7.
    // source is pre-swizzled: srcslot = (lane&7) ^ (lane>>3)   (n&7 == lane>>3)
    const int sh = lane >> 3, sl = lane & 7;
    const int srcslot = sl ^ sh;
    const bf16_t* ssrc[4];
    #pragma unroll
    for (int it = 0; it < 4; ++it) {
        int r = n0 + it * 32 + wave * 8 + sh;
        r = (r < Cn) ? r : (Cn - 1);            // clamp: last tile reads valid mem
        ssrc[it] = WbfT + (size_t)r * Dk + srcslot * 8;
    }
    bf16_t* sdst = &Blds[wave * 512];           // wave*1024 bytes (uniform per wave)

    #define STAGE(koff) do {                                                        \
        _Pragma("unroll")                                                           \
        for (int it_ = 0; it_ < 4; ++it_)                                           \
            __builtin_amdgcn_global_load_lds(                                       \
                (const __attribute__((address_space(1))) void*)(ssrc[it_] + (koff)),\
                (__attribute__((address_space(3))) void*)(sdst + it_ * 2048),       \
                16, 0, 0);                                                          \
    } while (0)

    f32x4 acc[4][4];
    #pragma unroll
    for (int i = 0; i < 4; ++i)
        #pragma unroll
        for (int j = 0; j < 4; ++j) acc[i][j] = (f32x4){0.f, 0.f, 0.f, 0.f};

    const bf16_t* abase = Xbf + (size_t)(m0 + wm * 64 + l16) * Dk + quad * 8;

    STAGE(0);
    for (int step = 0; step < 8; ++step) {      // BK=64, 8 K-steps
        __syncthreads();                         // tile 'step' resident (vmcnt drain)

        bf16x8 bfr[4][2];
        #pragma unroll
        for (int nl = 0; nl < 4; ++nl) {
            const int rn = wn * 64 + nl * 16 + l16;
            #pragma unroll
            for (int kk = 0; kk < 2; ++kk) {
                const int slot = (kk * 4 + quad) ^ (rn & 7);   // un-swizzle
                bfr[nl][kk] = *(const bf16x8*)&Blds[rn * 64 + slot * 8];
            }
        }
        bf16x8 af[4][2];
        #pragma unroll
        for (int mt = 0; mt < 4; ++mt)
            #pragma unroll
            for (int kk = 0; kk < 2; ++kk)
                af[mt][kk] = *(const bf16x8*)(abase + step * 64 + kk * 32
                                              + (size_t)mt * 16 * Dk);

        __syncthreads();                         // all reads of Blds done
        if (step < 7) STAGE((step + 1) * 64);    // async; flies under the MFMAs

        #pragma unroll
        for (int kk = 0; kk < 2; ++kk)
            #pragma unroll
            for (int mt = 0; mt < 4; ++mt)
                #pragma unroll
                for (int nl = 0; nl < 4; ++nl)
                    acc[mt][nl] = __builtin_amdgcn_mfma_f32_16x16x32_bf16(
                        af[mt][kk], bfr[nl][kk], acc[mt][nl], 0, 0, 0);
    }
    #undef STAGE

    // epilogue: clip, store cossim, accumulate exp row-sums (W already unit-norm)
    float eacc[4][4];
    #pragma unroll
    for (int i = 0; i < 4; ++i)
        #pragma unroll
        for (int j = 0; j < 4; ++j) eacc[i][j] = 0.f;

    #pragma unroll
    for (int mt = 0; mt < 4; ++mt) {
        const int mrow = m0 + wm * 64 + mt * 16 + quad * 4;
        #pragma unroll
        for (int nl = 0; nl < 4; ++nl) {
            const int ncol = wn * 64 + nl * 16 + l16;
            const int n = n0 + ncol;
            if (n < Cn) {
                #pragma unroll
                for (int reg = 0; reg < 4; ++reg) {
                    float v = acc[mt][nl][reg];
                    v = fminf(fmaxf(v, -1.f), 1.f);
                    out[(size_t)(mrow + reg) * Cn + n] = v;
                    eacc[mt][reg] += __expf(S_SCALE * v);
                }
            }
        }
    }
    #pragma unroll
    for (int mt = 0; mt < 4; ++mt)
        #pragma unroll
        for (int reg = 0; reg < 4; ++reg) {
            float e = eacc[mt][reg];
            #pragma unroll
            for (int off = 1; off < 16; off <<= 1) e += __shfl_xor(e, off);
            if (l16 == 0)
                rsbuf[(wm * 64 + mt * 16 + quad * 4 + reg) * 2 + wn] = e;
        }
    __syncthreads();
    if (tid < 128)
        part[(size_t)(m0 + tid) * NTP + nt] = rsbuf[tid * 2] + rsbuf[tid * 2 + 1];
}

// ---------------------------------------------------------------------------
// legacy GEMM (fallback if workspace < 107MB): previous verified kernel.
// ---------------------------------------------------------------------------
__global__ __launch_bounds__(256) void k_gemm_legacy(const float* __restrict__ W,
                                                     const bf16_t* __restrict__ Xbf,
                                                     float* __restrict__ out,
                                                     float* __restrict__ part) {
    __shared__ bf16_t Blds[BN * LDB_L];
    __shared__ float  nsqbuf[BN * 8];
    __shared__ float  wninv[BN];
    __shared__ float  rsbuf[128 * 2];

    const int id    = blockIdx.x;
    const int nt    = (id >> 6) * 8 + (id & 7);
    const int mt8   = (id >> 3) & 7;
    if (nt >= NT) return;
    const int n0 = nt * BN;
    const int m0 = mt8 * 128;

    const int tid  = threadIdx.x;
    const int wave = tid >> 6, lane = tid & 63;
    const int wm   = wave >> 1, wn = wave & 1;
    const int quad = lane >> 4, l16 = lane & 15;

    const int ng = tid >> 3, kg = tid & 7;
    const int n_loc = ng * 4, k_loc = kg * 4;
    const bool svalid = (n0 + n_loc) < Cn;
    const float* wrow = W + (size_t)k_loc * Cn + (n0 + n_loc);

    f32x4 acc[4][4];
    #pragma unroll
    for (int i = 0; i < 4; ++i)
        #pragma unroll
        for (int j = 0; j < 4; ++j) acc[i][j] = (f32x4){0.f, 0.f, 0.f, 0.f};

    float nsq0 = 0.f, nsq1 = 0.f, nsq2 = 0.f, nsq3 = 0.f;

    const float4 fz = make_float4(0.f, 0.f, 0.f, 0.f);
    float4 r0 = fz, r1 = fz, r2 = fz, r3 = fz;
    if (svalid) {
        r0 = *(const float4*)(wrow);
        r1 = *(const float4*)(wrow + (size_t)Cn);
        r2 = *(const float4*)(wrow + (size_t)2 * Cn);
        r3 = *(const float4*)(wrow + (size_t)3 * Cn);
    }

    const bf16_t* abase = Xbf + (size_t)(m0 + wm * 64 + l16) * Dk + quad * 8;

    #pragma unroll 2
    for (int step = 0; step < NSTEP_L; ++step) {
        __syncthreads();
        nsq0 += r0.x*r0.x + r1.x*r1.x + r2.x*r2.x + r3.x*r3.x;
        nsq1 += r0.y*r0.y + r1.y*r1.y + r2.y*r2.y + r3.y*r3.y;
        nsq2 += r0.z*r0.z + r1.z*r1.z + r2.z*r2.z + r3.z*r3.z;
        nsq3 += r0.w*r0.w + r1.w*r1.w + r2.w*r2.w + r3.w*r3.w;
        {
            bf16x4 p;
            p[0]=(bf16_t)r0.x; p[1]=(bf16_t)r1.x; p[2]=(bf16_t)r2.x; p[3]=(bf16_t)r3.x;
            *(bf16x4*)&Blds[(n_loc + 0) * LDB_L + k_loc] = p;
            p[0]=(bf16_t)r0.y; p[1]=(bf16_t)r1.y; p[2]=(bf16_t)r2.y; p[3]=(bf16_t)r3.y;
            *(bf16x4*)&Blds[(n_loc + 1) * LDB_L + k_loc] = p;
            p[0]=(bf16_t)r0.z; p[1]=(bf16_t)r1.z; p[2]=(bf16_t)r2.z; p[3]=(bf16_t)r3.z;
            *(bf16x4*)&Blds[(n_loc + 2) * LDB_L + k_loc] = p;
            p[0]=(bf16_t)r0.w; p[1]=(bf16_t)r1.w; p[2]=(bf16_t)r2.w; p[3]=(bf16_t)r3.w;
            *(bf16x4*)&Blds[(n_loc + 3) * LDB_L + k_loc] = p;
        }
        __syncthreads();

        float4 q0 = fz, q1 = fz, q2 = fz, q3 = fz;
        if ((step + 1 < NSTEP_L) && svalid) {
            const float* pp = wrow + (size_t)((step + 1) * BK_L) * Cn;
            q0 = *(const float4*)(pp);
            q1 = *(const float4*)(pp + (size_t)Cn);
            q2 = *(const float4*)(pp + (size_t)2 * Cn);
            q3 = *(const float4*)(pp + (size_t)3 * Cn);
        }

        const bf16_t* ab = abase + step * BK_L;
        bf16x8 af[4];
        #pragma unroll
        for (int mt = 0; mt < 4; ++mt)
            af[mt] = *(const bf16x8*)(ab + (size_t)mt * 16 * Dk);
        bf16x8 bfr[4];
        #pragma unroll
        for (int nl = 0; nl < 4; ++nl)
            bfr[nl] = *(const bf16x8*)&Blds[(wn * 64 + nl * 16 + l16) * LDB_L + quad * 8];

        #pragma unroll
        for (int mt = 0; mt < 4; ++mt)
            #pragma unroll
            for (int nl = 0; nl < 4; ++nl)
                acc[mt][nl] = __builtin_amdgcn_mfma_f32_16x16x32_bf16(
                    af[mt], bfr[nl], acc[mt][nl], 0, 0, 0);

        r0 = q0; r1 = q1; r2 = q2; r3 = q3;
    }

    __syncthreads();
    nsqbuf[(n_loc + 0) * 8 + kg] = nsq0;
    nsqbuf[(n_loc + 1) * 8 + kg] = nsq1;
    nsqbuf[(n_loc + 2) * 8 + kg] = nsq2;
    nsqbuf[(n_loc + 3) * 8 + kg] = nsq3;
    __syncthreads();
    if (tid < BN) {
        float s = 0.f;
        #pragma unroll
        for (int i = 0; i < 8; ++i) s += nsqbuf[tid * 8 + i];
        wninv[tid] = rsqrtf(fmaxf(s, 1e-24f));
    }
    __syncthreads();

    float eacc[4][4];
    #pragma unroll
    for (int i = 0; i < 4; ++i)
        #pragma unroll
        for (int j = 0; j < 4; ++j) eacc[i][j] = 0.f;

    #pragma unroll
    for (int mt = 0; mt < 4; ++mt) {
        const int mrow = m0 + wm * 64 + mt * 16 + quad * 4;
        #pragma unroll
        for (int nl = 0; nl < 4; ++nl) {
            const int ncol = wn * 64 + nl * 16 + l16;
            const int n = n0 + ncol;
            if (n < Cn) {
                const float inv = wninv[ncol];
                #pragma unroll
                for (int reg = 0; reg < 4; ++reg) {
                    float v = acc[mt][nl][reg] * inv;
                    v = fminf(fmaxf(v, -1.f), 1.f);
                    out[(size_t)(mrow + reg) * Cn + n] = v;
                    eacc[mt][reg] += __expf(S_SCALE * v);
                }
            }
        }
    }
    #pragma unroll
    for (int mt = 0; mt < 4; ++mt)
        #pragma unroll
        for (int reg = 0; reg < 4; ++reg) {
            float e = eacc[mt][reg];
            #pragma unroll
            for (int off = 1; off < 16; off <<= 1) e += __shfl_xor(e, off);
            if (l16 == 0)
                rsbuf[(wm * 64 + mt * 16 + quad * 4 + reg) * 2 + wn] = e;
        }
    __syncthreads();
    if (tid < 128)
        part[(size_t)(m0 + tid) * NTP + nt] = rsbuf[tid * 2] + rsbuf[tid * 2 + 1];
}

// ---------------------------------------------------------------------------
// per-row: sum 782 partials, gather target, compute per-row loss term
// ---------------------------------------------------------------------------
__global__ __launch_bounds__(256) void k_row(const float* __restrict__ part,
                                             const float* __restrict__ out,
                                             const int* __restrict__ label,
                                             float* __restrict__ Lbuf) {
    const int b = blockIdx.x, tid = threadIdx.x;
    float s = 0.f;
    const float* p = part + (size_t)b * NTP;
    for (int i = tid; i < NT; i += 256) s += p[i];
    #pragma unroll
    for (int off = 1; off < 64; off <<= 1) s += __shfl_xor(s, off);
    __shared__ float wsum[4];
    if ((tid & 63) == 0) wsum[tid >> 6] = s;
    __syncthreads();
    if (tid == 0) {
        const float rowsum = wsum[0] + wsum[1] + wsum[2] + wsum[3];
        const int c = label[b];
        const float tgt = out[(size_t)b * Cn + c];
        const float num = S_SCALE * (tgt - MARGIN);
        const float excl = rowsum - __expf(S_SCALE * tgt);
        Lbuf[b] = num - __logf(__expf(num) + excl);
    }
}

// ---------------------------------------------------------------------------
// final: loss = -mean(L)
// ---------------------------------------------------------------------------
__global__ __launch_bounds__(256) void k_loss(const float* __restrict__ Lbuf,
                                              float* __restrict__ out) {
    const int tid = threadIdx.x;
    float s = 0.f;
    for (int i = tid; i < Bm; i += 256) s += Lbuf[i];
    #pragma unroll
    for (int off = 1; off < 64; off <<= 1) s += __shfl_xor(s, off);
    __shared__ float wsum[4];
    if ((tid & 63) == 0) wsum[tid >> 6] = s;
    __syncthreads();
    if (tid == 0)
        out[(size_t)Bm * Cn] = -(wsum[0] + wsum[1] + wsum[2] + wsum[3]) / (float)Bm;
}

// ---------------------------------------------------------------------------
extern "C" void kernel_launch(void* const* d_in, const int* in_sizes, int n_in,
                              void* d_out, int out_size, void* d_ws, size_t ws_size,
                              hipStream_t stream) {
    const float* x     = (const float*)d_in[0];
    const float* W     = (const float*)d_in[1];
    const int*   label = (const int*)d_in[2];
    float* out = (float*)d_out;

    if (ws_size >= NEED_FAST) {
        // fast path: WbfT | Xbf | part | Lbuf
        bf16_t* WbfT = (bf16_t*)d_ws;
        bf16_t* Xbf  = (bf16_t*)((char*)d_ws + WBFT_B);
        float*  part = (float*)((char*)d_ws + WBFT_B + XBF_B);
        float*  Lbuf = (float*)((char*)d_ws + WBFT_B + XBF_B + PART_B);

        k_prep_x<<<Bm, 64, 0, stream>>>(x, Xbf);
        k_prep_w<<<(Cn + PC - 1) / PC, 256, 0, stream>>>(W, WbfT);   // 1563 blocks
        k_gemm<<<98 * 64, 256, 0, stream>>>(WbfT, Xbf, out, part);   // 6272 blocks
        k_row<<<Bm, 256, 0, stream>>>(part, out, label, Lbuf);
        k_loss<<<1, 256, 0, stream>>>(Lbuf, out);
    } else {
        // fallback: previous verified path (fits ~4.3MB workspace)
        bf16_t* Xbf  = (bf16_t*)d_ws;
        float*  part = (float*)((char*)d_ws + (1 << 20));
        float*  Lbuf = (float*)((char*)d_ws + (1 << 20) + (size_t)Bm * NTP * 4);

        k_prep_x<<<Bm, 64, 0, stream>>>(x, Xbf);
        k_gemm_legacy<<<98 * 64, 256, 0, stream>>>(W, Xbf, out, part);
        k_row<<<Bm, 256, 0, stream>>>(part, out, label, Lbuf);
        k_loss<<<1, 256, 0, stream>>>(Lbuf, out);
    }
}

// Round 2
// 830.852 us; speedup vs baseline: 1.1183x; 1.0592x over previous
//
#include <hip/hip_runtime.h>
#include <hip/hip_bf16.h>
#include <cstdint>
#include <cstddef>

// Problem constants
constexpr int   Bm = 1024;      // batch (M)
constexpr int   Dk = 512;       // feature dim (K)
constexpr int   Cn = 100000;    // classes (N)
constexpr float S_SCALE = 30.0f;
constexpr float MARGIN  = 0.4f;

static_assert(Cn % 4 == 0, "N must be multiple of 4 for float4 loads");

typedef __bf16 bf16_t;
typedef __bf16 bf16x4 __attribute__((ext_vector_type(4)));
typedef __bf16 bf16x8 __attribute__((ext_vector_type(8)));
typedef float  f32x4  __attribute__((ext_vector_type(4)));

constexpr int BN    = 128;                  // N tile
constexpr int NT    = (Cn + BN - 1) / BN;   // 782 n-tiles
constexpr int NTP   = 784;                  // padded partials stride

// fast-path workspace layout
constexpr size_t WBFT_B    = (size_t)Cn * Dk * 2;   // 102,400,000 B (normalized W^T bf16)
constexpr size_t XBF_B     = (size_t)Bm * Dk * 2;   // 1 MiB
constexpr size_t PART_B    = (size_t)Bm * NTP * 4;  // 3,211,264 B
constexpr size_t NEED_FAST = WBFT_B + XBF_B + PART_B + 4096;

// legacy-path constants
constexpr int BK_L    = 32;
constexpr int NSTEP_L = Dk / BK_L;          // 16
constexpr int LDB_L   = 40;

// ---------------------------------------------------------------------------
// prep: L2-normalize rows of x, store bf16. One wave per row.
// ---------------------------------------------------------------------------
__global__ __launch_bounds__(64) void k_prep_x(const float* __restrict__ x,
                                               bf16_t* __restrict__ Xbf) {
    const int row  = blockIdx.x;
    const int lane = threadIdx.x;
    const float* xp = x + (size_t)row * Dk + lane * 8;
    float4 a = *(const float4*)xp;
    float4 b = *(const float4*)(xp + 4);
    float s = a.x*a.x + a.y*a.y + a.z*a.z + a.w*a.w
            + b.x*b.x + b.y*b.y + b.z*b.z + b.w*b.w;
    #pragma unroll
    for (int off = 1; off < 64; off <<= 1) s += __shfl_xor(s, off);
    const float inv = rsqrtf(fmaxf(s, 1e-24f));   // == 1/clip(||x||,1e-12)
    bf16x8 v;
    v[0] = (bf16_t)(a.x * inv); v[1] = (bf16_t)(a.y * inv);
    v[2] = (bf16_t)(a.z * inv); v[3] = (bf16_t)(a.w * inv);
    v[4] = (bf16_t)(b.x * inv); v[5] = (bf16_t)(b.y * inv);
    v[6] = (bf16_t)(b.z * inv); v[7] = (bf16_t)(b.w * inv);
    *(bf16x8*)(Xbf + (size_t)row * Dk + lane * 8) = v;
}

// ---------------------------------------------------------------------------
// prep W (fast path): per-column L2 norm (fp32, matches reference), then write
// WbfT[c][k] = bf16(W[k][c] / ||w_c||)  -- transposed, k-contiguous rows (1KB).
// ---------------------------------------------------------------------------
constexpr int PC = 64;   // columns per block
__global__ __launch_bounds__(256) void k_prep_w(const float* __restrict__ W,
                                                bf16_t* __restrict__ WbfT) {
    __shared__ alignas(16) bf16_t T[PC * Dk];   // 64 KiB, slot-swizzled rows
    __shared__ float nsqb[PC][4];
    __shared__ float invn[PC];

    const int c0  = blockIdx.x * PC;
    const int t   = threadIdx.x;
    const int col = t & 63, kg = t >> 6;        // 4 k-groups of 128
    const int c   = c0 + col;
    const bool cv = c < Cn;
    const float* p = W + (size_t)(kg * 128) * Cn + c;

    float nsq = 0.f;
    if (cv) {
        #pragma unroll 16
        for (int i = 0; i < 128; ++i) {
            const float v = p[(size_t)i * Cn];
            nsq += v * v;
        }
    }
    nsqb[col][kg] = nsq;
    __syncthreads();
    if (t < PC)
        invn[t] = rsqrtf(fmaxf(nsqb[t][0] + nsqb[t][1] + nsqb[t][2] + nsqb[t][3], 1e-24f));
    __syncthreads();

    const float inv = invn[col];
    if (cv) {
        #pragma unroll 2
        for (int s = 0; s < 16; ++s) {          // 16 slots of 8 k each per k-group
            bf16x8 v;
            #pragma unroll
            for (int j = 0; j < 8; ++j)
                v[j] = (bf16_t)(p[(size_t)(s * 8 + j) * Cn] * inv);
            const int slot = (kg * 16 + s) ^ (col & 7);   // XOR-swizzle (bank spread)
            *(bf16x8*)&T[col * Dk + slot * 8] = v;
        }
    }
    __syncthreads();

    // write out: each wave writes full 1KB rows, lane l = 16B chunk l (coalesced)
    const int wv = t >> 6, l = t & 63;
    #pragma unroll 4
    for (int rr = 0; rr < 16; ++rr) {
        const int r  = wv * 16 + rr;
        const int cc = c0 + r;
        if (cc < Cn) {
            bf16x8 v = *(const bf16x8*)&T[r * Dk + ((l ^ (r & 7)) * 8)];
            *(bf16x8*)(WbfT + (size_t)cc * Dk + l * 8) = v;
        }
    }
}

// ---------------------------------------------------------------------------
// fast GEMM v2: 3-buffer LDS rotation, ONE raw barrier per K-step, no vmcnt
// drains in the loop.  Residency invariant (in-order vmcnt retirement):
//   step i issues [ds_reads(P[i%3]), A-loads(i), STAGE(P[(i+2)%3], i+2)].
//   The compiler's wait for the last A-load of step i retires everything
//   older, including STAGE(i+1) -> tile i+1 resident before any wave passes
//   the step-i+1 barrier.  Buffer overwrite safety: P[(i+2)%3] was last read
//   at step i-1; those ds_reads were consumed by step i-1's own MFMAs, which
//   precede the step-i barrier.  sched_barrier(0) pins the issue order.
// ---------------------------------------------------------------------------
__global__ __launch_bounds__(256) void k_gemm(const bf16_t* __restrict__ WbfT,
                                              const bf16_t* __restrict__ Xbf,
                                              float* __restrict__ out,
                                              float* __restrict__ part) {
    __shared__ alignas(16) bf16_t Blds[3][BN * 64];   // 3 x 16KB rotating buffers
    __shared__ float rsbuf[128 * 2];

    const int id  = blockIdx.x;
    const int nt  = (id >> 6) * 8 + (id & 7);
    const int mt8 = (id >> 3) & 7;
    if (nt >= NT) return;
    const int n0 = nt * BN;
    const int m0 = mt8 * 128;

    const int tid  = threadIdx.x;
    const int wave = tid >> 6, lane = tid & 63;
    const int wm   = wave >> 1, wn = wave & 1;
    const int quad = lane >> 4, l16 = lane & 15;

    // staging: dest row n = it*32 + wave*8 + (lane>>3), dest slot = lane&7.
    // source is pre-swizzled: srcslot = (lane&7) ^ (lane>>3)
    const int sh = lane >> 3, sl = lane & 7;
    const int srcslot = sl ^ sh;
    const bf16_t* ssrc[4];
    #pragma unroll
    for (int it = 0; it < 4; ++it) {
        int r = n0 + it * 32 + wave * 8 + sh;
        r = (r < Cn) ? r : (Cn - 1);            // clamp: last tile reads valid mem
        ssrc[it] = WbfT + (size_t)r * Dk + srcslot * 8;
    }

    #define STAGE(buf, koff) do {                                                   \
        bf16_t* sdst_ = &Blds[(buf)][wave * 512];                                   \
        _Pragma("unroll")                                                           \
        for (int it_ = 0; it_ < 4; ++it_)                                           \
            __builtin_amdgcn_global_load_lds(                                       \
                (const __attribute__((address_space(1))) void*)(ssrc[it_] + (koff)),\
                (__attribute__((address_space(3))) void*)(sdst_ + it_ * 2048),      \
                16, 0, 0);                                                          \
    } while (0)

    f32x4 acc[4][4];
    #pragma unroll
    for (int i = 0; i < 4; ++i)
        #pragma unroll
        for (int j = 0; j < 4; ++j) acc[i][j] = (f32x4){0.f, 0.f, 0.f, 0.f};

    const bf16_t* abase = Xbf + (size_t)(m0 + wm * 64 + l16) * Dk + quad * 8;

    // prologue: 2 tiles in flight; wait only for tile 0 (4 newest stay out)
    STAGE(0, 0);
    STAGE(1, 64);
    asm volatile("s_waitcnt vmcnt(4)" ::: "memory");

    #pragma unroll
    for (int step = 0; step < 8; ++step) {      // BK=64, 8 K-steps
        const int cur = step % 3;
        __builtin_amdgcn_s_barrier();            // tile 'step' resident (invariant)
        __builtin_amdgcn_sched_barrier(0);

        bf16x8 bfr[4][2];
        #pragma unroll
        for (int nl = 0; nl < 4; ++nl) {
            const int rn = wn * 64 + nl * 16 + l16;
            #pragma unroll
            for (int kk = 0; kk < 2; ++kk) {
                const int slot = (kk * 4 + quad) ^ (rn & 7);   // un-swizzle
                bfr[nl][kk] = *(const bf16x8*)&Blds[cur][rn * 64 + slot * 8];
            }
        }
        bf16x8 af[4][2];
        #pragma unroll
        for (int mt = 0; mt < 4; ++mt)
            #pragma unroll
            for (int kk = 0; kk < 2; ++kk)
                af[mt][kk] = *(const bf16x8*)(abase + step * 64 + kk * 32
                                              + (size_t)mt * 16 * Dk);

        __builtin_amdgcn_sched_barrier(0);       // STAGE stays after A-loads
        if (step + 2 < 8) STAGE((step + 2) % 3, (step + 2) * 64);
        __builtin_amdgcn_sched_barrier(0);       // MFMAs stay after STAGE

        #pragma unroll
        for (int kk = 0; kk < 2; ++kk)
            #pragma unroll
            for (int mt = 0; mt < 4; ++mt)
                #pragma unroll
                for (int nl = 0; nl < 4; ++nl)
                    acc[mt][nl] = __builtin_amdgcn_mfma_f32_16x16x32_bf16(
                        af[mt][kk], bfr[nl][kk], acc[mt][nl], 0, 0, 0);
    }
    #undef STAGE

    // epilogue: clip, store cossim, accumulate exp row-sums (W already unit-norm)
    float eacc[4][4];
    #pragma unroll
    for (int i = 0; i < 4; ++i)
        #pragma unroll
        for (int j = 0; j < 4; ++j) eacc[i][j] = 0.f;

    #pragma unroll
    for (int mt = 0; mt < 4; ++mt) {
        const int mrow = m0 + wm * 64 + mt * 16 + quad * 4;
        #pragma unroll
        for (int nl = 0; nl < 4; ++nl) {
            const int ncol = wn * 64 + nl * 16 + l16;
            const int n = n0 + ncol;
            if (n < Cn) {
                #pragma unroll
                for (int reg = 0; reg < 4; ++reg) {
                    float v = acc[mt][nl][reg];
                    v = fminf(fmaxf(v, -1.f), 1.f);
                    out[(size_t)(mrow + reg) * Cn + n] = v;
                    eacc[mt][reg] += __expf(S_SCALE * v);
                }
            }
        }
    }
    #pragma unroll
    for (int mt = 0; mt < 4; ++mt)
        #pragma unroll
        for (int reg = 0; reg < 4; ++reg) {
            float e = eacc[mt][reg];
            #pragma unroll
            for (int off = 1; off < 16; off <<= 1) e += __shfl_xor(e, off);
            if (l16 == 0)
                rsbuf[(wm * 64 + mt * 16 + quad * 4 + reg) * 2 + wn] = e;
        }
    __syncthreads();
    if (tid < 128)
        part[(size_t)(m0 + tid) * NTP + nt] = rsbuf[tid * 2] + rsbuf[tid * 2 + 1];
}

// ---------------------------------------------------------------------------
// legacy GEMM (fallback if workspace < 107MB): previously verified kernel.
// ---------------------------------------------------------------------------
__global__ __launch_bounds__(256) void k_gemm_legacy(const float* __restrict__ W,
                                                     const bf16_t* __restrict__ Xbf,
                                                     float* __restrict__ out,
                                                     float* __restrict__ part) {
    __shared__ bf16_t Blds[BN * LDB_L];
    __shared__ float  nsqbuf[BN * 8];
    __shared__ float  wninv[BN];
    __shared__ float  rsbuf[128 * 2];

    const int id    = blockIdx.x;
    const int nt    = (id >> 6) * 8 + (id & 7);
    const int mt8   = (id >> 3) & 7;
    if (nt >= NT) return;
    const int n0 = nt * BN;
    const int m0 = mt8 * 128;

    const int tid  = threadIdx.x;
    const int wave = tid >> 6, lane = tid & 63;
    const int wm   = wave >> 1, wn = wave & 1;
    const int quad = lane >> 4, l16 = lane & 15;

    const int ng = tid >> 3, kg = tid & 7;
    const int n_loc = ng * 4, k_loc = kg * 4;
    const bool svalid = (n0 + n_loc) < Cn;
    const float* wrow = W + (size_t)k_loc * Cn + (n0 + n_loc);

    f32x4 acc[4][4];
    #pragma unroll
    for (int i = 0; i < 4; ++i)
        #pragma unroll
        for (int j = 0; j < 4; ++j) acc[i][j] = (f32x4){0.f, 0.f, 0.f, 0.f};

    float nsq0 = 0.f, nsq1 = 0.f, nsq2 = 0.f, nsq3 = 0.f;

    const float4 fz = make_float4(0.f, 0.f, 0.f, 0.f);
    float4 r0 = fz, r1 = fz, r2 = fz, r3 = fz;
    if (svalid) {
        r0 = *(const float4*)(wrow);
        r1 = *(const float4*)(wrow + (size_t)Cn);
        r2 = *(const float4*)(wrow + (size_t)2 * Cn);
        r3 = *(const float4*)(wrow + (size_t)3 * Cn);
    }

    const bf16_t* abase = Xbf + (size_t)(m0 + wm * 64 + l16) * Dk + quad * 8;

    #pragma unroll 2
    for (int step = 0; step < NSTEP_L; ++step) {
        __syncthreads();
        nsq0 += r0.x*r0.x + r1.x*r1.x + r2.x*r2.x + r3.x*r3.x;
        nsq1 += r0.y*r0.y + r1.y*r1.y + r2.y*r2.y + r3.y*r3.y;
        nsq2 += r0.z*r0.z + r1.z*r1.z + r2.z*r2.z + r3.z*r3.z;
        nsq3 += r0.w*r0.w + r1.w*r1.w + r2.w*r2.w + r3.w*r3.w;
        {
            bf16x4 p;
            p[0]=(bf16_t)r0.x; p[1]=(bf16_t)r1.x; p[2]=(bf16_t)r2.x; p[3]=(bf16_t)r3.x;
            *(bf16x4*)&Blds[(n_loc + 0) * LDB_L + k_loc] = p;
            p[0]=(bf16_t)r0.y; p[1]=(bf16_t)r1.y; p[2]=(bf16_t)r2.y; p[3]=(bf16_t)r3.y;
            *(bf16x4*)&Blds[(n_loc + 1) * LDB_L + k_loc] = p;
            p[0]=(bf16_t)r0.z; p[1]=(bf16_t)r1.z; p[2]=(bf16_t)r2.z; p[3]=(bf16_t)r3.z;
            *(bf16x4*)&Blds[(n_loc + 2) * LDB_L + k_loc] = p;
            p[0]=(bf16_t)r0.w; p[1]=(bf16_t)r1.w; p[2]=(bf16_t)r2.w; p[3]=(bf16_t)r3.w;
            *(bf16x4*)&Blds[(n_loc + 3) * LDB_L + k_loc] = p;
        }
        __syncthreads();

        float4 q0 = fz, q1 = fz, q2 = fz, q3 = fz;
        if ((step + 1 < NSTEP_L) && svalid) {
            const float* pp = wrow + (size_t)((step + 1) * BK_L) * Cn;
            q0 = *(const float4*)(pp);
            q1 = *(const float4*)(pp + (size_t)Cn);
            q2 = *(const float4*)(pp + (size_t)2 * Cn);
            q3 = *(const float4*)(pp + (size_t)3 * Cn);
        }

        const bf16_t* ab = abase + step * BK_L;
        bf16x8 af[4];
        #pragma unroll
        for (int mt = 0; mt < 4; ++mt)
            af[mt] = *(const bf16x8*)(ab + (size_t)mt * 16 * Dk);
        bf16x8 bfr[4];
        #pragma unroll
        for (int nl = 0; nl < 4; ++nl)
            bfr[nl] = *(const bf16x8*)&Blds[(wn * 64 + nl * 16 + l16) * LDB_L + quad * 8];

        #pragma unroll
        for (int mt = 0; mt < 4; ++mt)
            #pragma unroll
            for (int nl = 0; nl < 4; ++nl)
                acc[mt][nl] = __builtin_amdgcn_mfma_f32_16x16x32_bf16(
                    af[mt], bfr[nl], acc[mt][nl], 0, 0, 0);

        r0 = q0; r1 = q1; r2 = q2; r3 = q3;
    }

    __syncthreads();
    nsqbuf[(n_loc + 0) * 8 + kg] = nsq0;
    nsqbuf[(n_loc + 1) * 8 + kg] = nsq1;
    nsqbuf[(n_loc + 2) * 8 + kg] = nsq2;
    nsqbuf[(n_loc + 3) * 8 + kg] = nsq3;
    __syncthreads();
    if (tid < BN) {
        float s = 0.f;
        #pragma unroll
        for (int i = 0; i < 8; ++i) s += nsqbuf[tid * 8 + i];
        wninv[tid] = rsqrtf(fmaxf(s, 1e-24f));
    }
    __syncthreads();

    float eacc[4][4];
    #pragma unroll
    for (int i = 0; i < 4; ++i)
        #pragma unroll
        for (int j = 0; j < 4; ++j) eacc[i][j] = 0.f;

    #pragma unroll
    for (int mt = 0; mt < 4; ++mt) {
        const int mrow = m0 + wm * 64 + mt * 16 + quad * 4;
        #pragma unroll
        for (int nl = 0; nl < 4; ++nl) {
            const int ncol = wn * 64 + nl * 16 + l16;
            const int n = n0 + ncol;
            if (n < Cn) {
                const float inv = wninv[ncol];
                #pragma unroll
                for (int reg = 0; reg < 4; ++reg) {
                    float v = acc[mt][nl][reg] * inv;
                    v = fminf(fmaxf(v, -1.f), 1.f);
                    out[(size_t)(mrow + reg) * Cn + n] = v;
                    eacc[mt][reg] += __expf(S_SCALE * v);
                }
            }
        }
    }
    #pragma unroll
    for (int mt = 0; mt < 4; ++mt)
        #pragma unroll
        for (int reg = 0; reg < 4; ++reg) {
            float e = eacc[mt][reg];
            #pragma unroll
            for (int off = 1; off < 16; off <<= 1) e += __shfl_xor(e, off);
            if (l16 == 0)
                rsbuf[(wm * 64 + mt * 16 + quad * 4 + reg) * 2 + wn] = e;
        }
    __syncthreads();
    if (tid < 128)
        part[(size_t)(m0 + tid) * NTP + nt] = rsbuf[tid * 2] + rsbuf[tid * 2 + 1];
}

// ---------------------------------------------------------------------------
// per-row: sum 782 partials, gather target, compute per-row loss term
// ---------------------------------------------------------------------------
__global__ __launch_bounds__(256) void k_row(const float* __restrict__ part,
                                             const float* __restrict__ out,
                                             const int* __restrict__ label,
                                             float* __restrict__ Lbuf) {
    const int b = blockIdx.x, tid = threadIdx.x;
    float s = 0.f;
    const float* p = part + (size_t)b * NTP;
    for (int i = tid; i < NT; i += 256) s += p[i];
    #pragma unroll
    for (int off = 1; off < 64; off <<= 1) s += __shfl_xor(s, off);
    __shared__ float wsum[4];
    if ((tid & 63) == 0) wsum[tid >> 6] = s;
    __syncthreads();
    if (tid == 0) {
        const float rowsum = wsum[0] + wsum[1] + wsum[2] + wsum[3];
        const int c = label[b];
        const float tgt = out[(size_t)b * Cn + c];
        const float num = S_SCALE * (tgt - MARGIN);
        const float excl = rowsum - __expf(S_SCALE * tgt);
        Lbuf[b] = num - __logf(__expf(num) + excl);
    }
}

// ---------------------------------------------------------------------------
// final: loss = -mean(L)
// ---------------------------------------------------------------------------
__global__ __launch_bounds__(256) void k_loss(const float* __restrict__ Lbuf,
                                              float* __restrict__ out) {
    const int tid = threadIdx.x;
    float s = 0.f;
    for (int i = tid; i < Bm; i += 256) s += Lbuf[i];
    #pragma unroll
    for (int off = 1; off < 64; off <<= 1) s += __shfl_xor(s, off);
    __shared__ float wsum[4];
    if ((tid & 63) == 0) wsum[tid >> 6] = s;
    __syncthreads();
    if (tid == 0)
        out[(size_t)Bm * Cn] = -(wsum[0] + wsum[1] + wsum[2] + wsum[3]) / (float)Bm;
}

// ---------------------------------------------------------------------------
extern "C" void kernel_launch(void* const* d_in, const int* in_sizes, int n_in,
                              void* d_out, int out_size, void* d_ws, size_t ws_size,
                              hipStream_t stream) {
    const float* x     = (const float*)d_in[0];
    const float* W     = (const float*)d_in[1];
    const int*   label = (const int*)d_in[2];
    float* out = (float*)d_out;

    if (ws_size >= NEED_FAST) {
        // fast path: WbfT | Xbf | part | Lbuf
        bf16_t* WbfT = (bf16_t*)d_ws;
        bf16_t* Xbf  = (bf16_t*)((char*)d_ws + WBFT_B);
        float*  part = (float*)((char*)d_ws + WBFT_B + XBF_B);
        float*  Lbuf = (float*)((char*)d_ws + WBFT_B + XBF_B + PART_B);

        k_prep_x<<<Bm, 64, 0, stream>>>(x, Xbf);
        k_prep_w<<<(Cn + PC - 1) / PC, 256, 0, stream>>>(W, WbfT);   // 1563 blocks
        k_gemm<<<98 * 64, 256, 0, stream>>>(WbfT, Xbf, out, part);   // 6272 blocks
        k_row<<<Bm, 256, 0, stream>>>(part, out, label, Lbuf);
        k_loss<<<1, 256, 0, stream>>>(Lbuf, out);
    } else {
        // fallback: previous verified path (fits ~4.3MB workspace)
        bf16_t* Xbf  = (bf16_t*)d_ws;
        float*  part = (float*)((char*)d_ws + (1 << 20));
        float*  Lbuf = (float*)((char*)d_ws + (1 << 20) + (size_t)Bm * NTP * 4);

        k_prep_x<<<Bm, 64, 0, stream>>>(x, Xbf);
        k_gemm_legacy<<<98 * 64, 256, 0, stream>>>(W, Xbf, out, part);
        k_row<<<Bm, 256, 0, stream>>>(part, out, label, Lbuf);
        k_loss<<<1, 256, 0, stream>>>(Lbuf, out);
    }
}